// Round 12
// baseline (294.168 us; speedup 1.0000x reference)
//
#include <hip/hip_runtime.h>
#include <hip/hip_fp16.h>
#include <math.h>

// ---------------------------------------------------------------------------
// dual GAT (2 branches x 4 GATConv layers), N=20000 nodes, E=320000 edges.
// R11 changes vs R10:
//  - gemm_mfma: swapped MFMA operands (D^T) -> epilogue packs f16x4 (4x fewer
//    h stores); score tile stored as one float4 per lane-group
//  - gather128_f: 2 nodes per wave (paired chunks = 32 loads in flight,
//    batched tails, halved wave count / setup overhead)
// ---------------------------------------------------------------------------

#define WAVE 64
#define NBKP 320   // padded bucket count (N/64 = 313 actual)

typedef _Float16 f16;
typedef f16 f16x8 __attribute__((ext_vector_type(8)));
typedef f16 f16x4 __attribute__((ext_vector_type(4)));
typedef float f32x4 __attribute__((ext_vector_type(4)));

// ---- stage 1: per-(block,bucket) counts (LDS hist, no global atomics) ----
__global__ __launch_bounds__(256) void bucket_count(
        const int* __restrict__ ei0, const int* __restrict__ ei1,
        int* __restrict__ carr, int nbuk, int E, int tot) {
    __shared__ int h[NBKP];
    int br = blockIdx.y;
    const int* ei = br ? ei1 : ei0;
    for (int i = threadIdx.x; i < NBKP; i += 256) h[i] = 0;
    __syncthreads();
    for (int t = blockIdx.x * 256 + threadIdx.x; t < tot; t += 256 * 256) {
        int dst = (t < E) ? ei[E + t] : (t - E);
        atomicAdd(&h[dst >> 6], 1);
    }
    __syncthreads();
    int* c = carr + ((size_t)br * gridDim.x + blockIdx.x) * NBKP;
    for (int i = threadIdx.x; i < NBKP; i += 256) c[i] = h[i];
}

// ---- stage 2a: per-bucket exclusive prefix over the 256 blocks -----------
__global__ __launch_bounds__(256) void bucket_scan1(
        int* __restrict__ carr, int* __restrict__ btot, int nblk) {
    __shared__ int smem[256];
    int br = blockIdx.y, k = blockIdx.x;
    size_t idx = ((size_t)br * nblk + threadIdx.x) * NBKP + k;
    int v = carr[idx];
    smem[threadIdx.x] = v;
    __syncthreads();
    #pragma unroll
    for (int off = 1; off < 256; off <<= 1) {
        int t = (threadIdx.x >= off) ? smem[threadIdx.x - off] : 0;
        __syncthreads();
        smem[threadIdx.x] += t;
        __syncthreads();
    }
    carr[idx] = smem[threadIdx.x] - v;            // exclusive prefix
    if (threadIdx.x == 255) btot[br * NBKP + k] = smem[255];
}

// ---- stage 2b: bucket bases (512-thread LDS scan over bucket totals) -----
__global__ __launch_bounds__(512) void bucket_scan2(
        const int* __restrict__ btot, int* __restrict__ bbase, int nbuk) {
    __shared__ int smem[512];
    int br = blockIdx.y;
    int v = (threadIdx.x < nbuk) ? btot[br * NBKP + threadIdx.x] : 0;
    smem[threadIdx.x] = v;
    __syncthreads();
    #pragma unroll
    for (int off = 1; off < 512; off <<= 1) {
        int t = (threadIdx.x >= off) ? smem[threadIdx.x - off] : 0;
        __syncthreads();
        smem[threadIdx.x] += t;
        __syncthreads();
    }
    int* bb = bbase + br * (nbuk + 1);
    if (threadIdx.x < nbuk) bb[threadIdx.x] = smem[threadIdx.x] - v;
    if (threadIdx.x == nbuk - 1) bb[nbuk] = smem[threadIdx.x];
}

// ---- stage 3: deterministic-slot pair scatter into bucket regions --------
__global__ __launch_bounds__(256) void bucket_scatter(
        const int* __restrict__ ei0, const int* __restrict__ ei1,
        const int* __restrict__ carr, const int* __restrict__ bbase,
        long long* __restrict__ pbuf, int nbuk, int E, int tot) {
    __shared__ int base_s[NBKP];
    __shared__ int h[NBKP];
    int br = blockIdx.y;
    const int* ei = br ? ei1 : ei0;
    const int* offb = carr + ((size_t)br * gridDim.x + blockIdx.x) * NBKP;
    const int* bb = bbase + br * (nbuk + 1);
    long long* pb = pbuf + (size_t)br * tot;
    for (int i = threadIdx.x; i < NBKP; i += 256) {
        h[i] = 0;
        base_s[i] = (i < nbuk) ? (bb[i] + offb[i]) : 0;
    }
    __syncthreads();
    for (int t = blockIdx.x * 256 + threadIdx.x; t < tot; t += 256 * 256) {
        int src, dst;
        if (t < E) { src = ei[t]; dst = ei[E + t]; }
        else       { src = dst = t - E; }
        int k = dst >> 6;
        int r = atomicAdd(&h[k], 1);        // LDS rank
        pb[base_s[k] + r] = ((long long)dst << 32) | (unsigned)src;
    }
}

// ---- stage 4: per-bucket exact CSR + rowptr ------------------------------
__global__ __launch_bounds__(256) void bucket_finalize(
        const long long* __restrict__ pbuf, const int* __restrict__ bbase,
        int* __restrict__ rowptrb, int* __restrict__ csrb,
        int n, int nbuk, int tot, int np) {
    __shared__ int h64[64], excl[64], cur[64];
    int br = blockIdx.y, k = blockIdx.x;
    const int* bb = bbase + br * (nbuk + 1);
    const long long* pb = pbuf + (size_t)br * tot;
    int base = bb[k], endb = bb[k + 1], cnt = endb - base;
    int* rp = rowptrb + (size_t)br * np;
    int* cs = csrb + (size_t)br * tot;
    int d0 = k << 6;
    int nn = min(64, n - d0);
    if (threadIdx.x < 64) h64[threadIdx.x] = 0;
    __syncthreads();
    for (int i = threadIdx.x; i < cnt; i += 256) {
        int dst = (int)(pb[base + i] >> 32);
        atomicAdd(&h64[dst & 63], 1);
    }
    __syncthreads();
    if (threadIdx.x == 0) {
        int run = 0;
        for (int j = 0; j < 64; ++j) { excl[j] = run; run += h64[j]; }
    }
    __syncthreads();
    if (threadIdx.x < 64) cur[threadIdx.x] = excl[threadIdx.x];
    if (threadIdx.x < nn) rp[d0 + threadIdx.x] = base + excl[threadIdx.x];
    if (k == nbuk - 1 && threadIdx.x == 64) rp[n] = endb;
    __syncthreads();
    for (int i = threadIdx.x; i < cnt; i += 256) {
        long long p = pb[base + i];
        int dst = (int)(p >> 32), src = (int)(p & 0xffffffffLL);
        int slot = atomicAdd(&cur[dst & 63], 1);
        cs[base + slot] = src;
    }
}

// ---- score-weight tiles for ALL layers in one launch ---------------------
struct WsdArgs {
    const float* W[8];    // [layer*2+branch]
    const float* as[8];
    const float* ad[8];
};

__global__ __launch_bounds__(256) void wsd_all(WsdArgs a, f16* __restrict__ wsd) {
    int l = blockIdx.z, b = blockIdx.y;
    int fout = (l == 3) ? 64 : 128;
    int H    = (l == 3) ? 1 : 4;
    int C    = (l == 3) ? 64 : 32;
    const float* W   = a.W[l * 2 + b];
    const float* a_s = a.as[l * 2 + b];
    const float* a_d = a.ad[l * 2 + b];
    f16* out = wsd + ((size_t)(l * 2 + b)) * 16 * 128;
    int k = blockIdx.x * 16 + (threadIdx.x & 15);
    int sc = threadIdx.x >> 4;
    float sum = 0.f;
    if (sc < 2 * H) {
        int hd = (sc < H) ? sc : sc - H;
        const float* av = (sc < H) ? a_s : a_d;
        const float4* Wr = (const float4*)(W + (size_t)k * fout + hd * C);
        const float4* ar = (const float4*)(av + hd * C);
        for (int c = 0; c < (C >> 2); ++c) {
            float4 wv = Wr[c]; float4 a4 = ar[c];
            sum += wv.x * a4.x + wv.y * a4.y + wv.z * a4.z + wv.w * a4.w;
        }
    }
    out[sc * 128 + k] = (f16)sum;
}

// ---- MFMA GEMM (swapped operands): h = x@W + score cols ------------------
// acc[ct] = mfma(Wfrag, xfrag): D m-index = W-col-in-tile, n-index = x-row.
// Epilogue: lane packs 4 consecutive cols as f16x4 (one 8B store per ct);
// score tile: lane-group 0 -> ss float4, group 1 -> sd float4.
template <typename XT>
__global__ __launch_bounds__(256) void gemm_mfma(
        const XT* __restrict__ x0, const XT* __restrict__ x1,
        const float* __restrict__ W0, const float* __restrict__ W1,
        const f16* __restrict__ wsd,
        f16* __restrict__ hb, float* __restrict__ ssb, float* __restrict__ sdb,
        int n, int fout, int H) {
    __shared__ f16 xl[64 * 136];
    __shared__ f16 wl[80 * 136];
    int b = blockIdx.z;
    const XT* x = b ? x1 : x0;
    const float* W = b ? W1 : W0;
    f16* h = hb + (size_t)b * n * 128;
    float* ss = ssb + (size_t)b * n * 4;
    float* sd = sdb + (size_t)b * n * 4;
    int colbase = blockIdx.y * 64;
    bool last = (blockIdx.y == gridDim.y - 1);
    int lane = threadIdx.x & 63, w = threadIdx.x >> 6;

    {
        int c = threadIdx.x & 63, kb = (threadIdx.x >> 6) * 32;
        #pragma unroll 8
        for (int j = 0; j < 32; ++j)
            wl[c * 136 + kb + j] = (f16)W[(size_t)(kb + j) * fout + colbase + c];
    }
    if (last) {
        int c = threadIdx.x & 15, kb = (threadIdx.x >> 4) * 8;
        *(f16x8*)&wl[(64 + c) * 136 + kb] =
            *(const f16x8*)&wsd[(size_t)b * 2048 + c * 128 + kb];
    }
    __syncthreads();

    f16x8 B[5][4];
    #pragma unroll
    for (int ct = 0; ct < 5; ++ct)
        #pragma unroll
        for (int kc = 0; kc < 4; ++kc)
            B[ct][kc] = *(const f16x8*)
                &wl[(ct * 16 + (lane & 15)) * 136 + kc * 32 + (lane >> 4) * 8];

    for (int base = blockIdx.x * 64; base < n; base += gridDim.x * 64) {
        __syncthreads();
        {
            int r = threadIdx.x >> 2, k0 = (threadIdx.x & 3) * 32;
            int row = base + r;
            if (row < n) {
                if constexpr (sizeof(XT) == 4) {
                    const float4* x4 = (const float4*)x;
                    #pragma unroll
                    for (int j = 0; j < 8; ++j) {
                        float4 v = x4[(size_t)row * 32 + (k0 >> 2) + j];
                        f16x4 hv = {(f16)v.x, (f16)v.y, (f16)v.z, (f16)v.w};
                        *(f16x4*)&xl[r * 136 + k0 + 4 * j] = hv;
                    }
                } else {
                    const f16x8* x8 = (const f16x8*)x;
                    #pragma unroll
                    for (int j = 0; j < 4; ++j)
                        *(f16x8*)&xl[r * 136 + k0 + 8 * j] =
                            x8[(size_t)row * 16 + (k0 >> 3) + j];
                }
            } else {
                f16x4 z = {(f16)0.f, (f16)0.f, (f16)0.f, (f16)0.f};
                #pragma unroll
                for (int j = 0; j < 8; ++j)
                    *(f16x4*)&xl[r * 136 + k0 + 4 * j] = z;
            }
        }
        __syncthreads();

        f16x8 A[4];
        #pragma unroll
        for (int kc = 0; kc < 4; ++kc)
            A[kc] = *(const f16x8*)
                &xl[(w * 16 + (lane & 15)) * 136 + kc * 32 + (lane >> 4) * 8];

        f32x4 acc[5];
        #pragma unroll
        for (int ct = 0; ct < 5; ++ct) acc[ct] = (f32x4){0.f, 0.f, 0.f, 0.f};
        #pragma unroll
        for (int ct = 0; ct < 5; ++ct)
            #pragma unroll
            for (int kc = 0; kc < 4; ++kc)
                acc[ct] = __builtin_amdgcn_mfma_f32_16x16x32_f16(
                    B[ct][kc], A[kc], acc[ct], 0, 0, 0);   // swapped: D^T

        // epilogue (transposed D): xrow = lane&15, cols = cg*4 + reg
        int xrow = base + w * 16 + (lane & 15);
        int cg = lane >> 4;
        if (xrow < n) {
            #pragma unroll
            for (int ct = 0; ct < 4; ++ct) {
                f16x4 hv = {(f16)acc[ct][0], (f16)acc[ct][1],
                            (f16)acc[ct][2], (f16)acc[ct][3]};
                *(f16x4*)&h[(size_t)xrow * fout + colbase + ct * 16 + cg * 4] = hv;
            }
            if (last) {
                if (H == 4) {
                    if (cg == 0)      *(float4*)&ss[(size_t)xrow * 4] = *(float4*)&acc[4];
                    else if (cg == 1) *(float4*)&sd[(size_t)xrow * 4] = *(float4*)&acc[4];
                } else {
                    if (cg == 0) { ss[xrow] = acc[4][0]; sd[xrow] = acc[4][1]; }
                }
            }
        }
    }
}

// ---- fused alpha + gather, 128-wide layers: 2 nodes per wave -------------
__global__ __launch_bounds__(256) void gather128_f(
        const __half2* __restrict__ h2, const float* __restrict__ ss,
        const float* __restrict__ sd, const int* __restrict__ rowptr,
        const int* __restrict__ csr, const float* __restrict__ bias,
        f16* __restrict__ out, int n) {
    int wid = threadIdx.x >> 6, lane = threadIdx.x & 63;
    int jw = blockIdx.x * 4 + wid;
    int v0 = 2 * jw, v1 = v0 + 1;
    if (v0 >= n) return;
    bool has1 = (v1 < n);
    int hd = lane >> 4, sub = lane & 15, hd16 = hd * 16;

    int beg0 = rowptr[v0], end0 = rowptr[v0 + 1];
    int beg1 = has1 ? rowptr[v1] : 0, end1 = has1 ? rowptr[v1 + 1] : 0;
    float sdh0 = sd[v0 * 4 + hd];
    float sdh1 = has1 ? sd[v1 * 4 + hd] : 0.f;

    float a00 = 0.f, a01 = 0.f, d0 = 0.f;
    float a10 = 0.f, a11 = 0.f, d1 = 0.f;
    int i0 = beg0, i1 = beg1;

    // paired full chunks: 32 h-loads in flight
    for (; i0 + 16 <= end0 && i1 + 16 <= end1; i0 += 16, i1 += 16) {
        int idx0 = csr[i0 + sub];
        int idx1 = csr[i1 + sub];
        float sc0 = ss[idx0 * 4 + hd] + sdh0; sc0 = fmaxf(sc0, 0.2f * sc0);
        float sc1 = ss[idx1 * 4 + hd] + sdh1; sc1 = fmaxf(sc1, 0.2f * sc1);
        float w0 = __expf(sc0), w1 = __expf(sc1);
        unsigned hv0[16], hv1[16];
        #pragma unroll
        for (int j = 0; j < 16; ++j) {
            int s = __shfl(idx0, j);
            hv0[j] = *(const unsigned*)&h2[s * 64 + lane];
        }
        #pragma unroll
        for (int j = 0; j < 16; ++j) {
            int s = __shfl(idx1, j);
            hv1[j] = *(const unsigned*)&h2[s * 64 + lane];
        }
        #pragma unroll
        for (int j = 0; j < 16; ++j) {
            float w = __shfl(w0, hd16 + j);
            float2 f = __half22float2(*(const __half2*)&hv0[j]);
            a00 = fmaf(w, f.x, a00); a01 = fmaf(w, f.y, a01); d0 += w;
        }
        #pragma unroll
        for (int j = 0; j < 16; ++j) {
            float w = __shfl(w1, hd16 + j);
            float2 f = __half22float2(*(const __half2*)&hv1[j]);
            a10 = fmaf(w, f.x, a10); a11 = fmaf(w, f.y, a11); d1 += w;
        }
    }
    // leftover full chunks (at most one loop runs)
    for (; i0 + 16 <= end0; i0 += 16) {
        int idx0 = csr[i0 + sub];
        float sc0 = ss[idx0 * 4 + hd] + sdh0; sc0 = fmaxf(sc0, 0.2f * sc0);
        float w0 = __expf(sc0);
        unsigned hv0[16];
        #pragma unroll
        for (int j = 0; j < 16; ++j) {
            int s = __shfl(idx0, j);
            hv0[j] = *(const unsigned*)&h2[s * 64 + lane];
        }
        #pragma unroll
        for (int j = 0; j < 16; ++j) {
            float w = __shfl(w0, hd16 + j);
            float2 f = __half22float2(*(const __half2*)&hv0[j]);
            a00 = fmaf(w, f.x, a00); a01 = fmaf(w, f.y, a01); d0 += w;
        }
    }
    for (; i1 + 16 <= end1; i1 += 16) {
        int idx1 = csr[i1 + sub];
        float sc1 = ss[idx1 * 4 + hd] + sdh1; sc1 = fmaxf(sc1, 0.2f * sc1);
        float w1 = __expf(sc1);
        unsigned hv1[16];
        #pragma unroll
        for (int j = 0; j < 16; ++j) {
            int s = __shfl(idx1, j);
            hv1[j] = *(const unsigned*)&h2[s * 64 + lane];
        }
        #pragma unroll
        for (int j = 0; j < 16; ++j) {
            float w = __shfl(w1, hd16 + j);
            float2 f = __half22float2(*(const __half2*)&hv1[j]);
            a10 = fmaf(w, f.x, a10); a11 = fmaf(w, f.y, a11); d1 += w;
        }
    }
    // batched tails
    {
        int rem0 = end0 - i0, rem1 = end1 - i1;
        int idx0 = (sub < rem0) ? csr[i0 + sub] : -1;
        int idx1 = (sub < rem1) ? csr[i1 + sub] : -1;
        float w0 = 0.f, w1 = 0.f;
        if (idx0 >= 0) {
            float sc = ss[idx0 * 4 + hd] + sdh0; sc = fmaxf(sc, 0.2f * sc);
            w0 = __expf(sc);
        }
        if (idx1 >= 0) {
            float sc = ss[idx1 * 4 + hd] + sdh1; sc = fmaxf(sc, 0.2f * sc);
            w1 = __expf(sc);
        }
        #pragma unroll 4
        for (int j = 0; j < rem0; ++j) {
            int s = __shfl(idx0, j);
            float w = __shfl(w0, hd16 + j);
            float2 f = __half22float2(h2[s * 64 + lane]);
            a00 = fmaf(w, f.x, a00); a01 = fmaf(w, f.y, a01); d0 += w;
        }
        #pragma unroll 4
        for (int j = 0; j < rem1; ++j) {
            int s = __shfl(idx1, j);
            float w = __shfl(w1, hd16 + j);
            float2 f = __half22float2(h2[s * 64 + lane]);
            a10 = fmaf(w, f.x, a10); a11 = fmaf(w, f.y, a11); d1 += w;
        }
    }

    float2 b2 = ((const float2*)bias)[lane];
    {
        float inv = 1.f / d0;
        float o0 = fmaxf(fmaf(a00, inv, b2.x), 0.f);
        float o1 = fmaxf(fmaf(a01, inv, b2.y), 0.f);
        __half2 ov = __floats2half2_rn(o0, o1);
        __builtin_nontemporal_store(*(unsigned int*)&ov,
                                    (unsigned int*)&out[v0 * 128 + 2 * lane]);
    }
    if (has1) {
        float inv = 1.f / d1;
        float o0 = fmaxf(fmaf(a10, inv, b2.x), 0.f);
        float o1 = fmaxf(fmaf(a11, inv, b2.y), 0.f);
        __half2 ov = __floats2half2_rn(o0, o1);
        __builtin_nontemporal_store(*(unsigned int*)&ov,
                                    (unsigned int*)&out[v1 * 128 + 2 * lane]);
    }
}

// ---- fused alpha + gather, layer 4, BOTH branches -> single d_out write --
__global__ __launch_bounds__(256) void gather64_both(
        const __half* __restrict__ h0, const __half* __restrict__ h1,
        const float* __restrict__ ss0, const float* __restrict__ ss1,
        const float* __restrict__ sd0, const float* __restrict__ sd1,
        const int* __restrict__ rp0, const int* __restrict__ rp1,
        const int* __restrict__ csr0, const int* __restrict__ csr1,
        const float* __restrict__ bias0, const float* __restrict__ bias1,
        float* __restrict__ out, int n) {
    int wid = threadIdx.x >> 6, lane = threadIdx.x & 63;
    int v = blockIdx.x * 4 + wid;
    if (v >= n) return;
    int sub = lane & 15;
    float og = 0.f;

    #pragma unroll
    for (int br = 0; br < 2; ++br) {
        const __half* h   = br ? h1 : h0;
        const float* ss   = br ? ss1 : ss0;
        const float* sd   = br ? sd1 : sd0;
        const int* rowptr = br ? rp1 : rp0;
        const int* csr    = br ? csr1 : csr0;
        const float* bias = br ? bias1 : bias0;
        int beg = rowptr[v], end = rowptr[v + 1];
        float sd_v = sd[v];
        float acc = 0.f, den = 0.f;
        int i0 = beg;
        for (; i0 + 16 <= end; i0 += 16) {
            int myidx = csr[i0 + sub];
            float sc = ss[myidx] + sd_v;
            sc = fmaxf(sc, 0.2f * sc);
            float w_reg = __expf(sc);
            unsigned short hv[16];
            #pragma unroll
            for (int j = 0; j < 16; ++j) {
                int s = __shfl(myidx, j);
                hv[j] = *(const unsigned short*)&h[s * 64 + lane];
            }
            #pragma unroll
            for (int j = 0; j < 16; ++j) {
                float w = __shfl(w_reg, j);
                float f = __half2float(*(const __half*)&hv[j]);
                acc = fmaf(w, f, acc);
                den += w;
            }
        }
        int rem = end - i0;
        if (rem > 0) {
            int myidx = (sub < rem) ? csr[i0 + sub] : -1;
            float w_reg = 0.f;
            if (myidx >= 0) {
                float sc = ss[myidx] + sd_v;
                sc = fmaxf(sc, 0.2f * sc);
                w_reg = __expf(sc);
            }
            #pragma unroll 4
            for (int j = 0; j < rem; ++j) {
                int s = __shfl(myidx, j);
                float w = __shfl(w_reg, j);
                float f = __half2float(h[s * 64 + lane]);
                acc = fmaf(w, f, acc);
                den += w;
            }
        }
        float o = acc / den + bias[lane];
        og += 0.5f / (1.f + __expf(-o));
    }
    out[(size_t)v * 64 + lane] = og;
}

extern "C" void kernel_launch(void* const* d_in, const int* in_sizes, int n_in,
                              void* d_out, int out_size, void* d_ws, size_t ws_size,
                              hipStream_t stream) {
    const int N = in_sizes[0] / 128;      // 20000
    const int E = in_sizes[1] / 2;        // 320000
    const int TOT = E + N;                // edges incl. self loops
    const int NP = N + 4;                 // rowptr stride
    const int NBUK = (N + 63) >> 6;       // 313 buckets of 64 nodes
    const int NBLK = 256;                 // count/scatter blocks per branch

    const float* x1 = (const float*)d_in[0];
    const int*   ei1 = (const int*)d_in[1];
    const float* x2 = (const float*)d_in[2];
    const int*   ei2 = (const int*)d_in[3];
    void* const* P0 = d_in + 4;
    void* const* P1 = d_in + 20;

    // workspace layout (8B-aligned chunks)
    char* w = (char*)d_ws;
    f16* bufX = (f16*)w;               w += (size_t)2 * N * 128 * 2;
    f16* bufH = (f16*)w;               w += (size_t)2 * N * 128 * 2;
    float* s_src = (float*)w;          w += (size_t)2 * N * 4 * 4;
    float* s_dst = (float*)w;          w += (size_t)2 * N * 4 * 4;
    int* rowptr = (int*)w;             w += (size_t)2 * NP * 4;
    int* csr_src = (int*)w;            w += (size_t)2 * TOT * 4;
    int* carr = (int*)w;               w += (size_t)2 * NBLK * NBKP * 4;
    int* btot = (int*)w;               w += (size_t)2 * NBKP * 4;
    int* bbase = (int*)w;              w += (size_t)2 * (NBUK + 1) * 4 + 8;
    long long* pbuf = (long long*)w;   w += (size_t)2 * TOT * 8;
    f16* wsd = (f16*)w;                w += (size_t)8 * 2048 * 2;

    dim3 blk(256);
    int gWave  = (N + 3) / 4;                 // 1-node-per-wave kernels
    int gWave2 = ((N + 1) / 2 + 3) / 4;       // 2-node-per-wave gather

    // ---- all score-weight tiles (weights-only dependency) ---------------
    WsdArgs wa;
    for (int l = 0; l < 4; ++l) {
        int o = (l < 3) ? l * 4 : 12;
        wa.W[l * 2 + 0]  = (const float*)P0[o + 0];
        wa.W[l * 2 + 1]  = (const float*)P1[o + 0];
        wa.as[l * 2 + 0] = (const float*)P0[o + 1];
        wa.as[l * 2 + 1] = (const float*)P1[o + 1];
        wa.ad[l * 2 + 0] = (const float*)P0[o + 2];
        wa.ad[l * 2 + 1] = (const float*)P1[o + 2];
    }
    wsd_all<<<dim3(8, 2, 4), blk, 0, stream>>>(wa, wsd);

    // ---- CSR build: bucketed counting sort, no global atomics -----------
    bucket_count<<<dim3(NBLK, 2), blk, 0, stream>>>(ei1, ei2, carr, NBUK, E, TOT);
    bucket_scan1<<<dim3(NBUK, 2), blk, 0, stream>>>(carr, btot, NBLK);
    bucket_scan2<<<dim3(1, 2), dim3(512), 0, stream>>>(btot, bbase, NBUK);
    bucket_scatter<<<dim3(NBLK, 2), blk, 0, stream>>>(ei1, ei2, carr, bbase,
                                                      pbuf, NBUK, E, TOT);
    bucket_finalize<<<dim3(NBUK, 2), blk, 0, stream>>>(pbuf, bbase, rowptr,
                                                       csr_src, N, NBUK, TOT, NP);

    // ---- layers 1..3 (128 -> 4x32, relu), gathers per-branch ------------
    for (int l = 0; l < 3; ++l) {
        if (l == 0)
            gemm_mfma<float><<<dim3(128, 2, 2), blk, 0, stream>>>(
                x1, x2,
                (const float*)P0[0], (const float*)P1[0],
                wsd + (size_t)l * 4096, bufH, s_src, s_dst, N, 128, 4);
        else
            gemm_mfma<f16><<<dim3(128, 2, 2), blk, 0, stream>>>(
                bufX, bufX + (size_t)N * 128,
                (const float*)P0[l*4+0], (const float*)P1[l*4+0],
                wsd + (size_t)l * 4096, bufH, s_src, s_dst, N, 128, 4);
        for (int b = 0; b < 2; ++b)
            gather128_f<<<gWave2, blk, 0, stream>>>(
                (const __half2*)(bufH + (size_t)b * N * 128),
                s_src + (size_t)b * N * 4, s_dst + (size_t)b * N * 4,
                rowptr + (size_t)b * NP, csr_src + (size_t)b * TOT,
                (const float*)(b ? P1[l*4+3] : P0[l*4+3]),
                bufX + (size_t)b * N * 128, N);
    }

    // ---- layer 4 (128 -> 1x64, sigmoid, both branches -> d_out) ---------
    gemm_mfma<f16><<<dim3(128, 1, 2), blk, 0, stream>>>(
        bufX, bufX + (size_t)N * 128,
        (const float*)P0[12], (const float*)P1[12],
        wsd + (size_t)3 * 4096, bufH, s_src, s_dst, N, 64, 1);
    gather64_both<<<gWave, blk, 0, stream>>>(
        (const __half*)bufH, (const __half*)(bufH + (size_t)N * 128),
        s_src, s_src + (size_t)N * 4, s_dst, s_dst + (size_t)N * 4,
        rowptr, rowptr + NP, csr_src, csr_src + (size_t)TOT,
        (const float*)P0[15], (const float*)P1[15],
        (float*)d_out, N);
}

// Round 13
// 255.100 us; speedup vs baseline: 1.1532x; 1.1532x over previous
//
#include <hip/hip_runtime.h>
#include <hip/hip_fp16.h>
#include <math.h>

// ---------------------------------------------------------------------------
// dual GAT (2 branches x 4 GATConv layers), N=20000 nodes, E=320000 edges.
// R12 = R10 revert (R11's swapped-gemm + 2-node gather both regressed) plus:
//  - nontemporal csr-index loads in gathers (csr is stream-once; keep L2 for h)
//  - den computed via 4-step shfl_xor group-reduce instead of 16 serial adds
// ---------------------------------------------------------------------------

#define WAVE 64
#define NBKP 320   // padded bucket count (N/64 = 313 actual)

typedef _Float16 f16;
typedef f16 f16x8 __attribute__((ext_vector_type(8)));
typedef f16 f16x4 __attribute__((ext_vector_type(4)));
typedef float f32x4 __attribute__((ext_vector_type(4)));

// ---- stage 1: per-(block,bucket) counts (LDS hist, no global atomics) ----
__global__ __launch_bounds__(256) void bucket_count(
        const int* __restrict__ ei0, const int* __restrict__ ei1,
        int* __restrict__ carr, int nbuk, int E, int tot) {
    __shared__ int h[NBKP];
    int br = blockIdx.y;
    const int* ei = br ? ei1 : ei0;
    for (int i = threadIdx.x; i < NBKP; i += 256) h[i] = 0;
    __syncthreads();
    for (int t = blockIdx.x * 256 + threadIdx.x; t < tot; t += 256 * 256) {
        int dst = (t < E) ? ei[E + t] : (t - E);
        atomicAdd(&h[dst >> 6], 1);
    }
    __syncthreads();
    int* c = carr + ((size_t)br * gridDim.x + blockIdx.x) * NBKP;
    for (int i = threadIdx.x; i < NBKP; i += 256) c[i] = h[i];
}

// ---- stage 2a: per-bucket exclusive prefix over the 256 blocks -----------
__global__ __launch_bounds__(256) void bucket_scan1(
        int* __restrict__ carr, int* __restrict__ btot, int nblk) {
    __shared__ int smem[256];
    int br = blockIdx.y, k = blockIdx.x;
    size_t idx = ((size_t)br * nblk + threadIdx.x) * NBKP + k;
    int v = carr[idx];
    smem[threadIdx.x] = v;
    __syncthreads();
    #pragma unroll
    for (int off = 1; off < 256; off <<= 1) {
        int t = (threadIdx.x >= off) ? smem[threadIdx.x - off] : 0;
        __syncthreads();
        smem[threadIdx.x] += t;
        __syncthreads();
    }
    carr[idx] = smem[threadIdx.x] - v;            // exclusive prefix
    if (threadIdx.x == 255) btot[br * NBKP + k] = smem[255];
}

// ---- stage 2b: bucket bases (512-thread LDS scan over bucket totals) -----
__global__ __launch_bounds__(512) void bucket_scan2(
        const int* __restrict__ btot, int* __restrict__ bbase, int nbuk) {
    __shared__ int smem[512];
    int br = blockIdx.y;
    int v = (threadIdx.x < nbuk) ? btot[br * NBKP + threadIdx.x] : 0;
    smem[threadIdx.x] = v;
    __syncthreads();
    #pragma unroll
    for (int off = 1; off < 512; off <<= 1) {
        int t = (threadIdx.x >= off) ? smem[threadIdx.x - off] : 0;
        __syncthreads();
        smem[threadIdx.x] += t;
        __syncthreads();
    }
    int* bb = bbase + br * (nbuk + 1);
    if (threadIdx.x < nbuk) bb[threadIdx.x] = smem[threadIdx.x] - v;
    if (threadIdx.x == nbuk - 1) bb[nbuk] = smem[threadIdx.x];
}

// ---- stage 3: deterministic-slot pair scatter into bucket regions --------
__global__ __launch_bounds__(256) void bucket_scatter(
        const int* __restrict__ ei0, const int* __restrict__ ei1,
        const int* __restrict__ carr, const int* __restrict__ bbase,
        long long* __restrict__ pbuf, int nbuk, int E, int tot) {
    __shared__ int base_s[NBKP];
    __shared__ int h[NBKP];
    int br = blockIdx.y;
    const int* ei = br ? ei1 : ei0;
    const int* offb = carr + ((size_t)br * gridDim.x + blockIdx.x) * NBKP;
    const int* bb = bbase + br * (nbuk + 1);
    long long* pb = pbuf + (size_t)br * tot;
    for (int i = threadIdx.x; i < NBKP; i += 256) {
        h[i] = 0;
        base_s[i] = (i < nbuk) ? (bb[i] + offb[i]) : 0;
    }
    __syncthreads();
    for (int t = blockIdx.x * 256 + threadIdx.x; t < tot; t += 256 * 256) {
        int src, dst;
        if (t < E) { src = ei[t]; dst = ei[E + t]; }
        else       { src = dst = t - E; }
        int k = dst >> 6;
        int r = atomicAdd(&h[k], 1);        // LDS rank
        pb[base_s[k] + r] = ((long long)dst << 32) | (unsigned)src;
    }
}

// ---- stage 4: per-bucket exact CSR + rowptr ------------------------------
__global__ __launch_bounds__(256) void bucket_finalize(
        const long long* __restrict__ pbuf, const int* __restrict__ bbase,
        int* __restrict__ rowptrb, int* __restrict__ csrb,
        int n, int nbuk, int tot, int np) {
    __shared__ int h64[64], excl[64], cur[64];
    int br = blockIdx.y, k = blockIdx.x;
    const int* bb = bbase + br * (nbuk + 1);
    const long long* pb = pbuf + (size_t)br * tot;
    int base = bb[k], endb = bb[k + 1], cnt = endb - base;
    int* rp = rowptrb + (size_t)br * np;
    int* cs = csrb + (size_t)br * tot;
    int d0 = k << 6;
    int nn = min(64, n - d0);
    if (threadIdx.x < 64) h64[threadIdx.x] = 0;
    __syncthreads();
    for (int i = threadIdx.x; i < cnt; i += 256) {
        int dst = (int)(pb[base + i] >> 32);
        atomicAdd(&h64[dst & 63], 1);
    }
    __syncthreads();
    if (threadIdx.x == 0) {
        int run = 0;
        for (int j = 0; j < 64; ++j) { excl[j] = run; run += h64[j]; }
    }
    __syncthreads();
    if (threadIdx.x < 64) cur[threadIdx.x] = excl[threadIdx.x];
    if (threadIdx.x < nn) rp[d0 + threadIdx.x] = base + excl[threadIdx.x];
    if (k == nbuk - 1 && threadIdx.x == 64) rp[n] = endb;
    __syncthreads();
    for (int i = threadIdx.x; i < cnt; i += 256) {
        long long p = pb[base + i];
        int dst = (int)(p >> 32), src = (int)(p & 0xffffffffLL);
        int slot = atomicAdd(&cur[dst & 63], 1);
        cs[base + slot] = src;
    }
}

// ---- score-weight tiles for ALL layers in one launch ---------------------
struct WsdArgs {
    const float* W[8];    // [layer*2+branch]
    const float* as[8];
    const float* ad[8];
};

__global__ __launch_bounds__(256) void wsd_all(WsdArgs a, f16* __restrict__ wsd) {
    int l = blockIdx.z, b = blockIdx.y;
    int fout = (l == 3) ? 64 : 128;
    int H    = (l == 3) ? 1 : 4;
    int C    = (l == 3) ? 64 : 32;
    const float* W   = a.W[l * 2 + b];
    const float* a_s = a.as[l * 2 + b];
    const float* a_d = a.ad[l * 2 + b];
    f16* out = wsd + ((size_t)(l * 2 + b)) * 16 * 128;
    int k = blockIdx.x * 16 + (threadIdx.x & 15);
    int sc = threadIdx.x >> 4;
    float sum = 0.f;
    if (sc < 2 * H) {
        int hd = (sc < H) ? sc : sc - H;
        const float* av = (sc < H) ? a_s : a_d;
        const float4* Wr = (const float4*)(W + (size_t)k * fout + hd * C);
        const float4* ar = (const float4*)(av + hd * C);
        for (int c = 0; c < (C >> 2); ++c) {
            float4 wv = Wr[c]; float4 a4 = ar[c];
            sum += wv.x * a4.x + wv.y * a4.y + wv.z * a4.z + wv.w * a4.w;
        }
    }
    out[sc * 128 + k] = (f16)sum;
}

// ---- MFMA GEMM: h = x@W (f32 acc, fp16 out) + score cols ----------------
template <typename XT>
__global__ __launch_bounds__(256) void gemm_mfma(
        const XT* __restrict__ x0, const XT* __restrict__ x1,
        const float* __restrict__ W0, const float* __restrict__ W1,
        const f16* __restrict__ wsd,
        f16* __restrict__ hb, float* __restrict__ ssb, float* __restrict__ sdb,
        int n, int fout, int H) {
    __shared__ f16 xl[64 * 136];
    __shared__ f16 wl[80 * 136];
    int b = blockIdx.z;
    const XT* x = b ? x1 : x0;
    const float* W = b ? W1 : W0;
    f16* h = hb + (size_t)b * n * 128;
    float* ss = ssb + (size_t)b * n * 4;
    float* sd = sdb + (size_t)b * n * 4;
    int colbase = blockIdx.y * 64;
    bool last = (blockIdx.y == gridDim.y - 1);
    int lane = threadIdx.x & 63, w = threadIdx.x >> 6;

    {
        int c = threadIdx.x & 63, kb = (threadIdx.x >> 6) * 32;
        #pragma unroll 8
        for (int j = 0; j < 32; ++j)
            wl[c * 136 + kb + j] = (f16)W[(size_t)(kb + j) * fout + colbase + c];
    }
    if (last) {
        int c = threadIdx.x & 15, kb = (threadIdx.x >> 4) * 8;
        *(f16x8*)&wl[(64 + c) * 136 + kb] =
            *(const f16x8*)&wsd[(size_t)b * 2048 + c * 128 + kb];
    }
    __syncthreads();

    f16x8 B[5][4];
    #pragma unroll
    for (int ct = 0; ct < 5; ++ct)
        #pragma unroll
        for (int kc = 0; kc < 4; ++kc)
            B[ct][kc] = *(const f16x8*)
                &wl[(ct * 16 + (lane & 15)) * 136 + kc * 32 + (lane >> 4) * 8];

    for (int base = blockIdx.x * 64; base < n; base += gridDim.x * 64) {
        __syncthreads();
        {
            int r = threadIdx.x >> 2, k0 = (threadIdx.x & 3) * 32;
            int row = base + r;
            if (row < n) {
                if constexpr (sizeof(XT) == 4) {
                    const float4* x4 = (const float4*)x;
                    #pragma unroll
                    for (int j = 0; j < 8; ++j) {
                        float4 v = x4[(size_t)row * 32 + (k0 >> 2) + j];
                        f16x4 hv = {(f16)v.x, (f16)v.y, (f16)v.z, (f16)v.w};
                        *(f16x4*)&xl[r * 136 + k0 + 4 * j] = hv;
                    }
                } else {
                    const f16x8* x8 = (const f16x8*)x;
                    #pragma unroll
                    for (int j = 0; j < 4; ++j)
                        *(f16x8*)&xl[r * 136 + k0 + 8 * j] =
                            x8[(size_t)row * 16 + (k0 >> 3) + j];
                }
            } else {
                f16x4 z = {(f16)0.f, (f16)0.f, (f16)0.f, (f16)0.f};
                #pragma unroll
                for (int j = 0; j < 8; ++j)
                    *(f16x4*)&xl[r * 136 + k0 + 4 * j] = z;
            }
        }
        __syncthreads();

        f16x8 A[4];
        #pragma unroll
        for (int kc = 0; kc < 4; ++kc)
            A[kc] = *(const f16x8*)
                &xl[(w * 16 + (lane & 15)) * 136 + kc * 32 + (lane >> 4) * 8];

        f32x4 acc[5];
        #pragma unroll
        for (int ct = 0; ct < 5; ++ct) acc[ct] = (f32x4){0.f, 0.f, 0.f, 0.f};
        #pragma unroll
        for (int ct = 0; ct < 5; ++ct)
            #pragma unroll
            for (int kc = 0; kc < 4; ++kc)
                acc[ct] = __builtin_amdgcn_mfma_f32_16x16x32_f16(
                    A[kc], B[ct][kc], acc[ct], 0, 0, 0);

        int r0 = base + w * 16 + (lane >> 4) * 4;
        int c0 = lane & 15;
        #pragma unroll
        for (int ct = 0; ct < 4; ++ct) {
            int col = colbase + ct * 16 + c0;
            #pragma unroll
            for (int j = 0; j < 4; ++j) {
                int row = r0 + j;
                if (row < n) h[(size_t)row * fout + col] = (f16)acc[ct][j];
            }
        }
        if (last) {
            #pragma unroll
            for (int j = 0; j < 4; ++j) {
                int row = r0 + j;
                if (row < n) {
                    float v = acc[4][j];
                    if (c0 < H)          ss[(size_t)row * H + c0] = v;
                    else if (c0 < 2 * H) sd[(size_t)row * H + c0 - H] = v;
                }
            }
        }
    }
}

// ---- fused alpha + gather, 128-wide layers (4 heads x 32) ---------------
// two-phase chunks (16 loads in flight), group-reduced den, nt csr loads.
__global__ __launch_bounds__(256) void gather128_f(
        const __half2* __restrict__ h2, const float* __restrict__ ss,
        const float* __restrict__ sd, const int* __restrict__ rowptr,
        const int* __restrict__ csr, const float* __restrict__ bias,
        f16* __restrict__ out, int n) {
    int wid = threadIdx.x >> 6, lane = threadIdx.x & 63;
    int v = blockIdx.x * 4 + wid;
    if (v >= n) return;
    int beg = rowptr[v], end = rowptr[v + 1];
    int hd = lane >> 4;
    int sub = lane & 15;
    int hd16 = hd * 16;
    float sd_h = sd[v * 4 + hd];

    float acc0 = 0.f, acc1 = 0.f, den = 0.f;
    int i0 = beg;
    for (; i0 + 16 <= end; i0 += 16) {
        int myidx = __builtin_nontemporal_load(&csr[i0 + sub]);
        float sc = ss[myidx * 4 + hd] + sd_h;
        sc = fmaxf(sc, 0.2f * sc);
        float w_reg = __expf(sc);
        unsigned hv[16];
        #pragma unroll
        for (int j = 0; j < 16; ++j) {
            int s = __shfl(myidx, j);
            hv[j] = *(const unsigned*)&h2[s * 64 + lane];
        }
        // den: group-reduce w_reg within this lane's 16-lane group
        {
            float r = w_reg;
            r += __shfl_xor(r, 1); r += __shfl_xor(r, 2);
            r += __shfl_xor(r, 4); r += __shfl_xor(r, 8);
            den += r;
        }
        #pragma unroll
        for (int j = 0; j < 16; ++j) {
            float w = __shfl(w_reg, hd16 + j);
            float2 f = __half22float2(*(const __half2*)&hv[j]);
            acc0 = fmaf(w, f.x, acc0);
            acc1 = fmaf(w, f.y, acc1);
        }
    }
    int rem = end - i0;
    if (rem > 0) {
        int myidx = (sub < rem) ? __builtin_nontemporal_load(&csr[i0 + sub]) : -1;
        float w_reg = 0.f;
        if (myidx >= 0) {
            float sc = ss[myidx * 4 + hd] + sd_h;
            sc = fmaxf(sc, 0.2f * sc);
            w_reg = __expf(sc);
        }
        {
            float r = w_reg;
            r += __shfl_xor(r, 1); r += __shfl_xor(r, 2);
            r += __shfl_xor(r, 4); r += __shfl_xor(r, 8);
            den += r;
        }
        #pragma unroll 4
        for (int j = 0; j < rem; ++j) {
            int s = __shfl(myidx, j);
            float w = __shfl(w_reg, hd16 + j);
            float2 f = __half22float2(h2[s * 64 + lane]);
            acc0 = fmaf(w, f.x, acc0);
            acc1 = fmaf(w, f.y, acc1);
        }
    }

    float inv = 1.f / den;
    float2 b2 = ((const float2*)bias)[lane];
    float o0 = fmaxf(fmaf(acc0, inv, b2.x), 0.f);
    float o1 = fmaxf(fmaf(acc1, inv, b2.y), 0.f);
    __half2 ov = __floats2half2_rn(o0, o1);
    __builtin_nontemporal_store(*(unsigned int*)&ov,
                                (unsigned int*)&out[v * 128 + 2 * lane]);
}

// ---- fused alpha + gather, layer 4, BOTH branches -> single d_out write --
__global__ __launch_bounds__(256) void gather64_both(
        const __half* __restrict__ h0, const __half* __restrict__ h1,
        const float* __restrict__ ss0, const float* __restrict__ ss1,
        const float* __restrict__ sd0, const float* __restrict__ sd1,
        const int* __restrict__ rp0, const int* __restrict__ rp1,
        const int* __restrict__ csr0, const int* __restrict__ csr1,
        const float* __restrict__ bias0, const float* __restrict__ bias1,
        float* __restrict__ out, int n) {
    int wid = threadIdx.x >> 6, lane = threadIdx.x & 63;
    int v = blockIdx.x * 4 + wid;
    if (v >= n) return;
    int sub = lane & 15;
    float og = 0.f;

    #pragma unroll
    for (int br = 0; br < 2; ++br) {
        const __half* h   = br ? h1 : h0;
        const float* ss   = br ? ss1 : ss0;
        const float* sd   = br ? sd1 : sd0;
        const int* rowptr = br ? rp1 : rp0;
        const int* csr    = br ? csr1 : csr0;
        const float* bias = br ? bias1 : bias0;
        int beg = rowptr[v], end = rowptr[v + 1];
        float sd_v = sd[v];
        float acc = 0.f, den = 0.f;
        int i0 = beg;
        for (; i0 + 16 <= end; i0 += 16) {
            int myidx = __builtin_nontemporal_load(&csr[i0 + sub]);
            float sc = ss[myidx] + sd_v;
            sc = fmaxf(sc, 0.2f * sc);
            float w_reg = __expf(sc);
            unsigned short hv[16];
            #pragma unroll
            for (int j = 0; j < 16; ++j) {
                int s = __shfl(myidx, j);
                hv[j] = *(const unsigned short*)&h[s * 64 + lane];
            }
            {
                float r = w_reg;
                r += __shfl_xor(r, 1); r += __shfl_xor(r, 2);
                r += __shfl_xor(r, 4); r += __shfl_xor(r, 8);
                den += r;
            }
            #pragma unroll
            for (int j = 0; j < 16; ++j) {
                float w = __shfl(w_reg, j);
                float f = __half2float(*(const __half*)&hv[j]);
                acc = fmaf(w, f, acc);
            }
        }
        int rem = end - i0;
        if (rem > 0) {
            int myidx = (sub < rem) ? __builtin_nontemporal_load(&csr[i0 + sub]) : -1;
            float w_reg = 0.f;
            if (myidx >= 0) {
                float sc = ss[myidx] + sd_v;
                sc = fmaxf(sc, 0.2f * sc);
                w_reg = __expf(sc);
            }
            {
                float r = w_reg;
                r += __shfl_xor(r, 1); r += __shfl_xor(r, 2);
                r += __shfl_xor(r, 4); r += __shfl_xor(r, 8);
                den += r;
            }
            #pragma unroll 4
            for (int j = 0; j < rem; ++j) {
                int s = __shfl(myidx, j);
                float w = __shfl(w_reg, j);
                float f = __half2float(h[s * 64 + lane]);
                acc = fmaf(w, f, acc);
            }
        }
        float o = acc / den + bias[lane];
        og += 0.5f / (1.f + __expf(-o));
    }
    out[(size_t)v * 64 + lane] = og;
}

extern "C" void kernel_launch(void* const* d_in, const int* in_sizes, int n_in,
                              void* d_out, int out_size, void* d_ws, size_t ws_size,
                              hipStream_t stream) {
    const int N = in_sizes[0] / 128;      // 20000
    const int E = in_sizes[1] / 2;        // 320000
    const int TOT = E + N;                // edges incl. self loops
    const int NP = N + 4;                 // rowptr stride
    const int NBUK = (N + 63) >> 6;       // 313 buckets of 64 nodes
    const int NBLK = 256;                 // count/scatter blocks per branch

    const float* x1 = (const float*)d_in[0];
    const int*   ei1 = (const int*)d_in[1];
    const float* x2 = (const float*)d_in[2];
    const int*   ei2 = (const int*)d_in[3];
    void* const* P0 = d_in + 4;
    void* const* P1 = d_in + 20;

    // workspace layout (8B-aligned chunks)
    char* w = (char*)d_ws;
    f16* bufX = (f16*)w;               w += (size_t)2 * N * 128 * 2;
    f16* bufH = (f16*)w;               w += (size_t)2 * N * 128 * 2;
    float* s_src = (float*)w;          w += (size_t)2 * N * 4 * 4;
    float* s_dst = (float*)w;          w += (size_t)2 * N * 4 * 4;
    int* rowptr = (int*)w;             w += (size_t)2 * NP * 4;
    int* csr_src = (int*)w;            w += (size_t)2 * TOT * 4;
    int* carr = (int*)w;               w += (size_t)2 * NBLK * NBKP * 4;
    int* btot = (int*)w;               w += (size_t)2 * NBKP * 4;
    int* bbase = (int*)w;              w += (size_t)2 * (NBUK + 1) * 4 + 8;
    long long* pbuf = (long long*)w;   w += (size_t)2 * TOT * 8;
    f16* wsd = (f16*)w;                w += (size_t)8 * 2048 * 2;

    dim3 blk(256);
    int gWave  = (N + 3) / 4;             // wave-per-node kernels

    // ---- all score-weight tiles (weights-only dependency) ---------------
    WsdArgs wa;
    for (int l = 0; l < 4; ++l) {
        int o = (l < 3) ? l * 4 : 12;
        wa.W[l * 2 + 0]  = (const float*)P0[o + 0];
        wa.W[l * 2 + 1]  = (const float*)P1[o + 0];
        wa.as[l * 2 + 0] = (const float*)P0[o + 1];
        wa.as[l * 2 + 1] = (const float*)P1[o + 1];
        wa.ad[l * 2 + 0] = (const float*)P0[o + 2];
        wa.ad[l * 2 + 1] = (const float*)P1[o + 2];
    }
    wsd_all<<<dim3(8, 2, 4), blk, 0, stream>>>(wa, wsd);

    // ---- CSR build: bucketed counting sort, no global atomics -----------
    bucket_count<<<dim3(NBLK, 2), blk, 0, stream>>>(ei1, ei2, carr, NBUK, E, TOT);
    bucket_scan1<<<dim3(NBUK, 2), blk, 0, stream>>>(carr, btot, NBLK);
    bucket_scan2<<<dim3(1, 2), dim3(512), 0, stream>>>(btot, bbase, NBUK);
    bucket_scatter<<<dim3(NBLK, 2), blk, 0, stream>>>(ei1, ei2, carr, bbase,
                                                      pbuf, NBUK, E, TOT);
    bucket_finalize<<<dim3(NBUK, 2), blk, 0, stream>>>(pbuf, bbase, rowptr,
                                                       csr_src, N, NBUK, TOT, NP);

    // ---- layers 1..3 (128 -> 4x32, relu), gathers per-branch ------------
    for (int l = 0; l < 3; ++l) {
        if (l == 0)
            gemm_mfma<float><<<dim3(128, 2, 2), blk, 0, stream>>>(
                x1, x2,
                (const float*)P0[0], (const float*)P1[0],
                wsd + (size_t)l * 4096, bufH, s_src, s_dst, N, 128, 4);
        else
            gemm_mfma<f16><<<dim3(128, 2, 2), blk, 0, stream>>>(
                bufX, bufX + (size_t)N * 128,
                (const float*)P0[l*4+0], (const float*)P1[l*4+0],
                wsd + (size_t)l * 4096, bufH, s_src, s_dst, N, 128, 4);
        for (int b = 0; b < 2; ++b)
            gather128_f<<<gWave, blk, 0, stream>>>(
                (const __half2*)(bufH + (size_t)b * N * 128),
                s_src + (size_t)b * N * 4, s_dst + (size_t)b * N * 4,
                rowptr + (size_t)b * NP, csr_src + (size_t)b * TOT,
                (const float*)(b ? P1[l*4+3] : P0[l*4+3]),
                bufX + (size_t)b * N * 128, N);
    }

    // ---- layer 4 (128 -> 1x64, sigmoid, both branches -> d_out) ---------
    gemm_mfma<f16><<<dim3(128, 1, 2), blk, 0, stream>>>(
        bufX, bufX + (size_t)N * 128,
        (const float*)P0[12], (const float*)P1[12],
        wsd + (size_t)3 * 4096, bufH, s_src, s_dst, N, 64, 1);
    gather64_both<<<gWave, blk, 0, stream>>>(
        (const __half*)bufH, (const __half*)(bufH + (size_t)N * 128),
        s_src, s_src + (size_t)N * 4, s_dst, s_dst + (size_t)N * 4,
        rowptr, rowptr + NP, csr_src, csr_src + (size_t)TOT,
        (const float*)P0[15], (const float*)P1[15],
        (float*)d_out, N);
}